// Round 1
// baseline (337.464 us; speedup 1.0000x reference)
//
#include <hip/hip_runtime.h>

#define DIM   256
#define BATCH 8192
#define MCELL 4096

// ---------------- helpers ----------------
__device__ __forceinline__ unsigned long long packMin(float v, unsigned idx) {
    unsigned u = __float_as_uint(v);
    u = (u & 0x80000000u) ? ~u : (u | 0x80000000u);   // order-preserving f32->u32
    return ((unsigned long long)u << 32) | (unsigned long long)idx;
}

// ---------------- scalar params: E[64] table + alpha ----------------
__global__ void k_scal(const int* __restrict__ epoch_p, float* __restrict__ scal) {
    int t = threadIdx.x;
    int raw = epoch_p[0];
    // defensive: accept int32 (expected) or float32 bit-pattern
    float ep = (raw >= 0 && raw < 100000) ? (float)raw : __int_as_float(raw);
    float radius = 32.0f - ep * (31.0f / 99.0f);
    float alpha  = 0.1f * (1.0f - ep / 100.0f);
    float rs = radius * 0.5f;
    float denom = 2.0f * rs * rs;
    if (t < 64)       scal[t]  = expf(-((float)(t * t)) / denom);
    else if (t == 64) scal[64] = alpha;
}

// ---------------- w2[m] = sum_d W[m,d]^2 ----------------
__global__ void k_w2(const float* __restrict__ W, float* __restrict__ w2) {
    int lane = threadIdx.x & 63;
    int row  = blockIdx.x * 4 + (threadIdx.x >> 6);
    float4 v = *(const float4*)(W + (size_t)row * DIM + lane * 4);
    float s = v.x * v.x + v.y * v.y + v.z * v.z + v.w * v.w;
    #pragma unroll
    for (int off = 32; off; off >>= 1) s += __shfl_down(s, off);
    if (lane == 0) w2[row] = s;
}

// ---------------- fused S = X*W^T + argmin_m (w2[m] - 2 S) ----------------
// grid: 1024 = 128 b-tiles x 8 m-splits; block 256 = 16(tx,m) x 16(ty,b)
__global__ __launch_bounds__(256, 4)
void k_gemm_argmin(const float* __restrict__ X, const float* __restrict__ W,
                   const float* __restrict__ w2, unsigned long long* __restrict__ packed) {
    __shared__ float Xs[32 * 64];    // [k][b-row]
    __shared__ float Ws[32 * 128];   // [k][m-col]
    const int tid = threadIdx.x;
    const int bb = blockIdx.x >> 3;
    const int ms = blockIdx.x & 7;
    const int b0 = bb * 64;
    const int mbase = ms * 512;
    const int tx = tid & 15;
    const int ty = tid >> 4;

    unsigned long long best[4] = {~0ull, ~0ull, ~0ull, ~0ull};

    for (int mt = 0; mt < 4; ++mt) {
        const int m0 = mbase + mt * 128;
        float acc[4][8];
        #pragma unroll
        for (int j = 0; j < 4; ++j)
            #pragma unroll
            for (int i = 0; i < 8; ++i) acc[j][i] = 0.0f;

        for (int c = 0; c < 8; ++c) {
            __syncthreads();
            { // stage X chunk [32k][64r], transposed, 2-way-bank-free writes
                const int r  = tid & 63;
                const int kg = (tid >> 6) * 8;
                const float* src = X + (size_t)(b0 + r) * DIM + c * 32 + kg;
                float4 v0 = *(const float4*)(src);
                float4 v1 = *(const float4*)(src + 4);
                Xs[(kg + 0) * 64 + r] = v0.x; Xs[(kg + 1) * 64 + r] = v0.y;
                Xs[(kg + 2) * 64 + r] = v0.z; Xs[(kg + 3) * 64 + r] = v0.w;
                Xs[(kg + 4) * 64 + r] = v1.x; Xs[(kg + 5) * 64 + r] = v1.y;
                Xs[(kg + 6) * 64 + r] = v1.z; Xs[(kg + 7) * 64 + r] = v1.w;
            }
            { // stage W chunk [32k][128m]
                const int mr  = tid & 127;
                const int kg2 = (tid >> 7) * 16;
                const float* src = W + (size_t)(m0 + mr) * DIM + c * 32 + kg2;
                #pragma unroll
                for (int i = 0; i < 4; ++i) {
                    float4 v = *(const float4*)(src + i * 4);
                    int kl = kg2 + i * 4;
                    Ws[(kl + 0) * 128 + mr] = v.x; Ws[(kl + 1) * 128 + mr] = v.y;
                    Ws[(kl + 2) * 128 + mr] = v.z; Ws[(kl + 3) * 128 + mr] = v.w;
                }
            }
            __syncthreads();
            #pragma unroll 8
            for (int k = 0; k < 32; ++k) {
                const float4 xa = *(const float4*)&Xs[k * 64 + ty * 4];
                const float4 wa = *(const float4*)&Ws[k * 128 + tx * 4];
                const float4 wb = *(const float4*)&Ws[k * 128 + 64 + tx * 4];
                float xv[4] = {xa.x, xa.y, xa.z, xa.w};
                float wv[8] = {wa.x, wa.y, wa.z, wa.w, wb.x, wb.y, wb.z, wb.w};
                #pragma unroll
                for (int j = 0; j < 4; ++j)
                    #pragma unroll
                    for (int i = 0; i < 8; ++i)
                        acc[j][i] = fmaf(xv[j], wv[i], acc[j][i]);
            }
        }
        // fold this m-tile into running best (ascending m order preserves ties)
        #pragma unroll
        for (int j = 0; j < 4; ++j)
            #pragma unroll
            for (int i = 0; i < 8; ++i) {
                const int lc = (i < 4) ? (tx * 4 + i) : (64 + tx * 4 + (i - 4));
                const int m = m0 + lc;
                const float val = w2[m] - 2.0f * acc[j][i];
                const unsigned long long p = packMin(val, (unsigned)m);
                if (p < best[j]) best[j] = p;
            }
    }
    // reduce across tx (16 lanes, in-wave), then global atomicMin
    #pragma unroll
    for (int j = 0; j < 4; ++j) {
        unsigned long long b = best[j];
        #pragma unroll
        for (int off = 8; off >= 1; off >>= 1) {
            unsigned long long o = __shfl_xor(b, off, 16);
            if (o < b) b = o;
        }
        if (tx == 0) atomicMin(&packed[b0 + ty * 4 + j], b);
    }
}

// ---------------- scatter: bmu_locs out + per-cell accumulation ----------------
__global__ void k_scatter(const unsigned long long* __restrict__ packed,
                          const float* __restrict__ X,
                          float* __restrict__ A, float* __restrict__ cnt,
                          float* __restrict__ out_locs) {
    const int b = blockIdx.x;
    const int m = (int)(packed[b] & 0xFFFFFFFFull);
    const int d = threadIdx.x;
    atomicAdd(&A[(size_t)m * DIM + d], X[(size_t)b * DIM + d]);
    if (d == 0) {
        atomicAdd(&cnt[m], 1.0f);
        out_locs[b * 2 + 0] = (float)(m >> 6);
        out_locs[b * 2 + 1] = (float)(m & 63);
    }
}

// ---------------- separable convolution pass 1 (over gj) ----------------
__global__ void k_conv1(const float* __restrict__ A, const float* __restrict__ E,
                        float* __restrict__ T1) {
    __shared__ float Es[64];
    const int d = threadIdx.x;
    if (d < 64) Es[d] = E[d];
    __syncthreads();
    const int gi = blockIdx.x >> 6, mj = blockIdx.x & 63;
    const float* base = A + (size_t)gi * 64 * DIM + d;
    float acc = 0.0f;
    #pragma unroll
    for (int gj = 0; gj < 64; ++gj) {
        int dd = mj - gj; dd = dd < 0 ? -dd : dd;
        acc += Es[dd] * base[(size_t)gj * DIM];
    }
    T1[(size_t)blockIdx.x * DIM + d] = acc;   // [gi][mj][d]
}

// ---------------- count convolutions (tiny) ----------------
__global__ void k_cnt1(const float* __restrict__ cnt, const float* __restrict__ E,
                       float* __restrict__ c1) {
    int t = blockIdx.x * 256 + threadIdx.x;   // 4096
    int gi = t >> 6, mj = t & 63;
    float acc = 0.0f;
    #pragma unroll
    for (int gj = 0; gj < 64; ++gj) {
        int dd = mj - gj; dd = dd < 0 ? -dd : dd;
        acc += E[dd] * cnt[gi * 64 + gj];
    }
    c1[gi * 64 + mj] = acc;
}
__global__ void k_cnt2(const float* __restrict__ c1, const float* __restrict__ E,
                       float* __restrict__ den) {
    int t = blockIdx.x * 256 + threadIdx.x;
    int mi = t >> 6, mj = t & 63;
    float acc = 0.0f;
    #pragma unroll
    for (int gi = 0; gi < 64; ++gi) {
        int dd = mi - gi; dd = dd < 0 ? -dd : dd;
        acc += E[dd] * c1[gi * 64 + mj];
    }
    den[mi * 64 + mj] = acc;
}

// ---------------- conv pass 2 (over gi) + divide + write ----------------
__global__ void k_conv2(const float* __restrict__ T1, const float* __restrict__ scal,
                        const float* __restrict__ den, float* __restrict__ outw) {
    __shared__ float Es[64];
    __shared__ float salpha;
    const int d = threadIdx.x;
    if (d < 64) Es[d] = scal[d];
    if (d == 64) salpha = scal[64];
    __syncthreads();
    const int mi = blockIdx.x >> 6, mj = blockIdx.x & 63;
    float acc = 0.0f;
    #pragma unroll
    for (int gi = 0; gi < 64; ++gi) {
        int dd = mi - gi; dd = dd < 0 ? -dd : dd;
        acc += Es[dd] * T1[((size_t)gi * 64 + mj) * DIM + d];
    }
    const float a = salpha;
    const float v = (a * acc) / (a * den[mi * 64 + mj] + 1e-12f);
    outw[((size_t)mi * 64 + mj) * DIM + d] = v;
}

// ---------------- launcher ----------------
extern "C" void kernel_launch(void* const* d_in, const int* in_sizes, int n_in,
                              void* d_out, int out_size, void* d_ws, size_t ws_size,
                              hipStream_t stream) {
    const float* X = (const float*)d_in[0];
    const float* W = (const float*)d_in[1];
    const int*   ep = (const int*)d_in[2];
    float* out = (float*)d_out;

    char* ws = (char*)d_ws;
    unsigned long long* packed = (unsigned long long*)(ws);        // 64 KB
    float* A    = (float*)(ws + 65536);                            // 4 MB
    float* cnt  = (float*)(ws + 4259840);                          // 16 KB
    float* w2   = (float*)(ws + 4276224);                          // 16 KB
    float* scal = (float*)(ws + 4292608);                          // E[64]+alpha
    float* T1   = (float*)(ws + 4293632);                          // 4 MB
    float* c1   = (float*)(ws + 8487936);                          // 16 KB
    float* den  = (float*)(ws + 8504320);                          // 16 KB

    hipMemsetAsync(packed, 0xFF, 65536, stream);                   // +inf packed
    hipMemsetAsync(ws + 65536, 0, 4194304 + 16384, stream);        // A + cnt = 0

    k_scal<<<1, 128, 0, stream>>>(ep, scal);
    k_w2<<<1024, 256, 0, stream>>>(W, w2);
    k_gemm_argmin<<<1024, 256, 0, stream>>>(X, W, w2, packed);
    k_scatter<<<BATCH, 256, 0, stream>>>(packed, X, A, cnt, out);
    k_conv1<<<4096, 256, 0, stream>>>(A, scal, T1);
    k_cnt1<<<16, 256, 0, stream>>>(cnt, scal, c1);
    k_cnt2<<<16, 256, 0, stream>>>(c1, scal, den);
    k_conv2<<<4096, 256, 0, stream>>>(T1, scal, den, out + 16384);
}

// Round 2
// 308.800 us; speedup vs baseline: 1.0928x; 1.0928x over previous
//
#include <hip/hip_runtime.h>

#define DIM   256
#define BATCH 8192
#define MCELL 4096

// ---------------- helpers ----------------
__device__ __forceinline__ unsigned long long packMin(float v, unsigned idx) {
    unsigned u = __float_as_uint(v);
    u = (u & 0x80000000u) ? ~u : (u | 0x80000000u);   // order-preserving f32->u32
    return ((unsigned long long)u << 32) | (unsigned long long)idx;
}

// ---------------- scalar params: E[64] table + alpha ----------------
__global__ void k_scal(const int* __restrict__ epoch_p, float* __restrict__ scal) {
    int t = threadIdx.x;
    int raw = epoch_p[0];
    float ep = (raw >= 0 && raw < 100000) ? (float)raw : __int_as_float(raw);
    float radius = 32.0f - ep * (31.0f / 99.0f);
    float alpha  = 0.1f * (1.0f - ep / 100.0f);
    float rs = radius * 0.5f;
    float denom = 2.0f * rs * rs;
    if (t < 64)       scal[t]  = expf(-((float)(t * t)) / denom);
    else if (t == 64) scal[64] = alpha;
}

// ---------------- w2[m] = sum_d W[m,d]^2 ----------------
__global__ void k_w2(const float* __restrict__ W, float* __restrict__ w2) {
    int lane = threadIdx.x & 63;
    int row  = blockIdx.x * 4 + (threadIdx.x >> 6);
    float4 v = *(const float4*)(W + (size_t)row * DIM + lane * 4);
    float s = v.x * v.x + v.y * v.y + v.z * v.z + v.w * v.w;
    #pragma unroll
    for (int off = 32; off; off >>= 1) s += __shfl_down(s, off);
    if (lane == 0) w2[row] = s;
}

// ---------------- fused S = X*W^T + argmin_m (w2[m] - 2 S) ----------------
// block tile 128(b) x 128(m), BK=32, 256 threads (16x16), 8x8 per thread.
// grid: 2048 = 64 b-tiles x 32 m-splits
__global__ __launch_bounds__(256, 4)
void k_gemm_argmin(const float* __restrict__ X, const float* __restrict__ W,
                   const float* __restrict__ w2, unsigned long long* __restrict__ packed) {
    __shared__ float Xs[32 * 128];   // [k][b-row]
    __shared__ float Ws[32 * 128];   // [k][m-col]
    const int tid = threadIdx.x;
    const int ms = blockIdx.x & 31;
    const int bb = blockIdx.x >> 5;
    const int b0 = bb * 128;
    const int m0 = ms * 128;
    const int tx = tid & 15;
    const int ty = tid >> 4;

    float acc[8][8];
    #pragma unroll
    for (int j = 0; j < 8; ++j)
        #pragma unroll
        for (int i = 0; i < 8; ++i) acc[j][i] = 0.0f;

    const int sr  = tid & 127;        // staging row (b or m)
    const int skg = (tid >> 7) * 16;  // staging k-group base

    for (int c = 0; c < 8; ++c) {
        __syncthreads();
        { // stage X chunk [32k][128b], transposed; scalar writes lane-consecutive -> conflict-free
            const float* src = X + (size_t)(b0 + sr) * DIM + c * 32 + skg;
            #pragma unroll
            for (int q = 0; q < 4; ++q) {
                float4 v = *(const float4*)(src + q * 4);
                const int kl = skg + q * 4;
                Xs[(kl + 0) * 128 + sr] = v.x; Xs[(kl + 1) * 128 + sr] = v.y;
                Xs[(kl + 2) * 128 + sr] = v.z; Xs[(kl + 3) * 128 + sr] = v.w;
            }
        }
        { // stage W chunk [32k][128m]
            const float* src = W + (size_t)(m0 + sr) * DIM + c * 32 + skg;
            #pragma unroll
            for (int q = 0; q < 4; ++q) {
                float4 v = *(const float4*)(src + q * 4);
                const int kl = skg + q * 4;
                Ws[(kl + 0) * 128 + sr] = v.x; Ws[(kl + 1) * 128 + sr] = v.y;
                Ws[(kl + 2) * 128 + sr] = v.z; Ws[(kl + 3) * 128 + sr] = v.w;
            }
        }
        __syncthreads();
        #pragma unroll 4
        for (int k = 0; k < 32; ++k) {
            const float4 xa = *(const float4*)&Xs[k * 128 + ty * 4];
            const float4 xb = *(const float4*)&Xs[k * 128 + 64 + ty * 4];
            const float4 wa = *(const float4*)&Ws[k * 128 + tx * 4];
            const float4 wb = *(const float4*)&Ws[k * 128 + 64 + tx * 4];
            const float xv[8] = {xa.x, xa.y, xa.z, xa.w, xb.x, xb.y, xb.z, xb.w};
            const float wv[8] = {wa.x, wa.y, wa.z, wa.w, wb.x, wb.y, wb.z, wb.w};
            #pragma unroll
            for (int j = 0; j < 8; ++j)
                #pragma unroll
                for (int i = 0; i < 8; ++i)
                    acc[j][i] = fmaf(xv[j], wv[i], acc[j][i]);
        }
    }

    // epilogue: distances + argmin fold
    float w2m[8];
    #pragma unroll
    for (int i = 0; i < 8; ++i) {
        const int mc = (i < 4) ? (tx * 4 + i) : (64 + tx * 4 + (i - 4));
        w2m[i] = w2[m0 + mc];
    }
    #pragma unroll
    for (int j = 0; j < 8; ++j) {
        unsigned long long best = ~0ull;
        #pragma unroll
        for (int i = 0; i < 8; ++i) {
            const int mc = (i < 4) ? (tx * 4 + i) : (64 + tx * 4 + (i - 4));
            const float val = w2m[i] - 2.0f * acc[j][i];
            const unsigned long long p = packMin(val, (unsigned)(m0 + mc));
            if (p < best) best = p;
        }
        // reduce across tx (16 lanes)
        #pragma unroll
        for (int off = 8; off >= 1; off >>= 1) {
            unsigned long long o = __shfl_xor(best, off, 16);
            if (o < best) best = o;
        }
        if (tx == 0) {
            const int rl = (j < 4) ? (ty * 4 + j) : (64 + ty * 4 + (j - 4));
            atomicMin(&packed[b0 + rl], best);
        }
    }
}

// ---------------- scatter: bmu_locs out + per-cell accumulation ----------------
__global__ void k_scatter(const unsigned long long* __restrict__ packed,
                          const float* __restrict__ X,
                          float* __restrict__ A, float* __restrict__ cnt,
                          float* __restrict__ out_locs) {
    const int b = blockIdx.x;
    const int m = (int)(packed[b] & 0xFFFFFFFFull);
    const int d = threadIdx.x;
    atomicAdd(&A[(size_t)m * DIM + d], X[(size_t)b * DIM + d]);
    if (d == 0) {
        atomicAdd(&cnt[m], 1.0f);
        out_locs[b * 2 + 0] = (float)(m >> 6);
        out_locs[b * 2 + 1] = (float)(m & 63);
    }
}

// ---------------- separable convolution pass 1 (over gj) ----------------
__global__ void k_conv1(const float* __restrict__ A, const float* __restrict__ E,
                        float* __restrict__ T1) {
    __shared__ float Es[64];
    const int d = threadIdx.x;
    if (d < 64) Es[d] = E[d];
    __syncthreads();
    const int gi = blockIdx.x >> 6, mj = blockIdx.x & 63;
    const float* base = A + (size_t)gi * 64 * DIM + d;
    float acc = 0.0f;
    #pragma unroll
    for (int gj = 0; gj < 64; ++gj) {
        int dd = mj - gj; dd = dd < 0 ? -dd : dd;
        acc += Es[dd] * base[(size_t)gj * DIM];
    }
    T1[(size_t)blockIdx.x * DIM + d] = acc;   // [gi][mj][d]
}

// ---------------- count convolutions (tiny) ----------------
__global__ void k_cnt1(const float* __restrict__ cnt, const float* __restrict__ E,
                       float* __restrict__ c1) {
    int t = blockIdx.x * 256 + threadIdx.x;   // 4096
    int gi = t >> 6, mj = t & 63;
    float acc = 0.0f;
    #pragma unroll
    for (int gj = 0; gj < 64; ++gj) {
        int dd = mj - gj; dd = dd < 0 ? -dd : dd;
        acc += E[dd] * cnt[gi * 64 + gj];
    }
    c1[gi * 64 + mj] = acc;
}
__global__ void k_cnt2(const float* __restrict__ c1, const float* __restrict__ E,
                       float* __restrict__ den) {
    int t = blockIdx.x * 256 + threadIdx.x;
    int mi = t >> 6, mj = t & 63;
    float acc = 0.0f;
    #pragma unroll
    for (int gi = 0; gi < 64; ++gi) {
        int dd = mi - gi; dd = dd < 0 ? -dd : dd;
        acc += E[dd] * c1[gi * 64 + mj];
    }
    den[mi * 64 + mj] = acc;
}

// ---------------- conv pass 2 (over gi) + divide + write ----------------
__global__ void k_conv2(const float* __restrict__ T1, const float* __restrict__ scal,
                        const float* __restrict__ den, float* __restrict__ outw) {
    __shared__ float Es[64];
    __shared__ float salpha;
    const int d = threadIdx.x;
    if (d < 64) Es[d] = scal[d];
    if (d == 64) salpha = scal[64];
    __syncthreads();
    const int mi = blockIdx.x >> 6, mj = blockIdx.x & 63;
    float acc = 0.0f;
    #pragma unroll
    for (int gi = 0; gi < 64; ++gi) {
        int dd = mi - gi; dd = dd < 0 ? -dd : dd;
        acc += Es[dd] * T1[((size_t)gi * 64 + mj) * DIM + d];
    }
    const float a = salpha;
    const float v = (a * acc) / (a * den[mi * 64 + mj] + 1e-12f);
    outw[((size_t)mi * 64 + mj) * DIM + d] = v;
}

// ---------------- launcher ----------------
extern "C" void kernel_launch(void* const* d_in, const int* in_sizes, int n_in,
                              void* d_out, int out_size, void* d_ws, size_t ws_size,
                              hipStream_t stream) {
    const float* X = (const float*)d_in[0];
    const float* W = (const float*)d_in[1];
    const int*   ep = (const int*)d_in[2];
    float* out = (float*)d_out;

    char* ws = (char*)d_ws;
    unsigned long long* packed = (unsigned long long*)(ws);        // 64 KB
    float* A    = (float*)(ws + 65536);                            // 4 MB
    float* cnt  = (float*)(ws + 4259840);                          // 16 KB
    float* w2   = (float*)(ws + 4276224);                          // 16 KB
    float* scal = (float*)(ws + 4292608);                          // E[64]+alpha
    float* T1   = (float*)(ws + 4293632);                          // 4 MB
    float* c1   = (float*)(ws + 8487936);                          // 16 KB
    float* den  = (float*)(ws + 8504320);                          // 16 KB

    hipMemsetAsync(packed, 0xFF, 65536, stream);                   // +inf packed
    hipMemsetAsync(ws + 65536, 0, 4194304 + 16384, stream);        // A + cnt = 0

    k_scal<<<1, 128, 0, stream>>>(ep, scal);
    k_w2<<<1024, 256, 0, stream>>>(W, w2);
    k_gemm_argmin<<<2048, 256, 0, stream>>>(X, W, w2, packed);
    k_scatter<<<BATCH, 256, 0, stream>>>(packed, X, A, cnt, out);
    k_conv1<<<4096, 256, 0, stream>>>(A, scal, T1);
    k_cnt1<<<16, 256, 0, stream>>>(cnt, scal, c1);
    k_cnt2<<<16, 256, 0, stream>>>(c1, scal, den);
    k_conv2<<<4096, 256, 0, stream>>>(T1, scal, den, out + 16384);
}

// Round 3
// 256.716 us; speedup vs baseline: 1.3145x; 1.2029x over previous
//
#include <hip/hip_runtime.h>

#define DIM   256
#define BATCH 8192
#define MCELL 4096

typedef unsigned long long u64;
typedef unsigned short u16;
typedef __attribute__((ext_vector_type(8))) short bf16x8;   // 8 bf16 = 4 VGPRs
typedef __attribute__((ext_vector_type(4))) float f32x4;

// ---------------- helpers ----------------
__device__ __forceinline__ u64 packMin(float v, unsigned idx) {
    unsigned u = __float_as_uint(v);
    u = (u & 0x80000000u) ? ~u : (u | 0x80000000u);   // order-preserving f32->u32
    return ((u64)u << 32) | (u64)idx;
}
__device__ __forceinline__ u16 f2bf(float f) {        // RN-even f32->bf16 (bits)
    unsigned u = __float_as_uint(f);
    u += 0x7fffu + ((u >> 16) & 1u);
    return (u16)(u >> 16);
}

// ---------------- scalar params: E[64] table + alpha ----------------
__global__ void k_scal(const int* __restrict__ epoch_p, float* __restrict__ scal) {
    int t = threadIdx.x;
    int raw = epoch_p[0];
    float ep = (raw >= 0 && raw < 100000) ? (float)raw : __int_as_float(raw);
    float radius = 32.0f - ep * (31.0f / 99.0f);
    float alpha  = 0.1f * (1.0f - ep / 100.0f);
    float rs = radius * 0.5f;
    float denom = 2.0f * rs * rs;
    if (t < 64)       scal[t]  = expf(-((float)(t * t)) / denom);
    else if (t == 64) scal[64] = alpha;
}

// ---------------- w2[m] = sum_d W[m,d]^2 ----------------
__global__ void k_w2(const float* __restrict__ W, float* __restrict__ w2) {
    int lane = threadIdx.x & 63;
    int row  = blockIdx.x * 4 + (threadIdx.x >> 6);
    float4 v = *(const float4*)(W + (size_t)row * DIM + lane * 4);
    float s = v.x * v.x + v.y * v.y + v.z * v.z + v.w * v.w;
    #pragma unroll
    for (int off = 32; off; off >>= 1) s += __shfl_down(s, off);
    if (lane == 0) w2[row] = s;
}

// ---------------- hi/lo bf16 split ----------------
__global__ void k_split(const float* __restrict__ src, u16* __restrict__ hi,
                        u16* __restrict__ lo, int n4) {
    int i = blockIdx.x * 256 + threadIdx.x;
    if (i >= n4) return;
    float4 v = ((const float4*)src)[i];
    float f[4] = {v.x, v.y, v.z, v.w};
    u16 h[4], l[4];
    #pragma unroll
    for (int q = 0; q < 4; ++q) {
        h[q] = f2bf(f[q]);
        float hf = __uint_as_float((unsigned)h[q] << 16);
        l[q] = f2bf(f[q] - hf);
    }
    ushort4 hv = {h[0], h[1], h[2], h[3]}, lv = {l[0], l[1], l[2], l[3]};
    ((ushort4*)hi)[i] = hv;
    ((ushort4*)lo)[i] = lv;
}

// ---------------- MFMA split-bf16 GEMM + per-row global top-2 ----------------
// grid 1024 = 64 b-tiles(128) x 16 m-tiles(256); 4 waves = 2b x 2m, wave tile 64b x 128m.
// No LDS, no barriers: A/B fragments are direct per-lane 16B global loads.
__global__ __launch_bounds__(256, 2)
void k_gemm_argmin(const u16* __restrict__ Xh, const u16* __restrict__ Xl,
                   const u16* __restrict__ Wh, const u16* __restrict__ Wl,
                   const float* __restrict__ w2,
                   u64* __restrict__ P1, u64* __restrict__ P2) {
    const int wg  = blockIdx.x;
    const int swz = (wg & 7) * 128 + (wg >> 3);   // XCD-chunked (1024 % 8 == 0, bijective)
    const int bt  = swz >> 4;
    const int mt  = swz & 15;
    const int wid  = threadIdx.x >> 6;
    const int lane = threadIdx.x & 63;
    const int b0 = bt * 128 + (wid >> 1) * 64;
    const int m0 = mt * 256 + (wid & 1) * 128;
    const int r = lane & 15;
    const int g = lane >> 4;

    const u16* xh = Xh + (size_t)(b0 + r) * DIM + g * 8;
    const u16* xl = Xl + (size_t)(b0 + r) * DIM + g * 8;
    const u16* wh = Wh + (size_t)(m0 + r) * DIM + g * 8;
    const u16* wl = Wl + (size_t)(m0 + r) * DIM + g * 8;

    f32x4 acc[4][8];
    #pragma unroll
    for (int i = 0; i < 4; ++i)
        #pragma unroll
        for (int j = 0; j < 8; ++j) acc[i][j] = (f32x4){0.f, 0.f, 0.f, 0.f};

    #pragma unroll 2
    for (int c = 0; c < 8; ++c) {
        const int ko = c * 32;
        bf16x8 ah[4], al[4];
        #pragma unroll
        for (int i = 0; i < 4; ++i) {
            ah[i] = *(const bf16x8*)(xh + (size_t)i * 16 * DIM + ko);
            al[i] = *(const bf16x8*)(xl + (size_t)i * 16 * DIM + ko);
        }
        #pragma unroll
        for (int j = 0; j < 8; ++j) {
            bf16x8 bh = *(const bf16x8*)(wh + (size_t)j * 16 * DIM + ko);
            bf16x8 bl = *(const bf16x8*)(wl + (size_t)j * 16 * DIM + ko);
            #pragma unroll
            for (int i = 0; i < 4; ++i) {
                acc[i][j] = __builtin_amdgcn_mfma_f32_16x16x32_bf16(ah[i], bh, acc[i][j], 0, 0, 0);
                acc[i][j] = __builtin_amdgcn_mfma_f32_16x16x32_bf16(ah[i], bl, acc[i][j], 0, 0, 0);
                acc[i][j] = __builtin_amdgcn_mfma_f32_16x16x32_bf16(al[i], bh, acc[i][j], 0, 0, 0);
            }
        }
    }

    // epilogue: d~ = w2[m] - 2*dot; per-row (i,q,g) top-2 over the wave's 128 m
    float w2v[8];
    #pragma unroll
    for (int j = 0; j < 8; ++j) w2v[j] = w2[m0 + j * 16 + r];

    #pragma unroll
    for (int i = 0; i < 4; ++i) {
        #pragma unroll
        for (int q = 0; q < 4; ++q) {
            u64 best = ~0ull, sec = ~0ull;
            #pragma unroll
            for (int j = 0; j < 8; ++j) {
                float d = w2v[j] - 2.0f * acc[i][j][q];
                u64 p = packMin(d, (unsigned)(m0 + j * 16 + r));
                if (p < best) { sec = best; best = p; }
                else if (p < sec) { sec = p; }
            }
            #pragma unroll
            for (int off = 1; off <= 8; off <<= 1) {   // reduce 16 lanes (same g)
                u64 ob = __shfl_xor(best, off);
                u64 os = __shfl_xor(sec, off);
                u64 nb  = ob < best ? ob : best;
                u64 hi2 = ob < best ? best : ob;
                u64 ns  = os < sec ? os : sec;
                ns = hi2 < ns ? hi2 : ns;
                best = nb; sec = ns;
            }
            if (r == 0) {
                const int row = b0 + i * 16 + g * 4 + q;
                u64 old = atomicMin(&P1[row], best);
                u64 c2 = (best < old) ? (old < sec ? old : sec) : best;
                atomicMin(&P2[row], c2);   // P2 ends as exact global 2nd-best
            }
        }
    }
}

// ---------------- exact f32 recheck of the two candidates ----------------
__global__ void k_recheck(const u64* __restrict__ P1, const u64* __restrict__ P2,
                          const float* __restrict__ X, const float* __restrict__ W,
                          const float* __restrict__ w2, int* __restrict__ bmu,
                          float* __restrict__ out_locs) {
    const int row  = blockIdx.x * 4 + (threadIdx.x >> 6);
    const int lane = threadIdx.x & 63;
    const int m1 = (int)(P1[row] & 0xFFFFFFFFull);
    const int m2 = (int)(P2[row] & 0xFFFFFFFFull);
    const float4 xv = *(const float4*)(X + (size_t)row * DIM + lane * 4);
    const float4 a  = *(const float4*)(W + (size_t)m1 * DIM + lane * 4);
    const float4 b  = *(const float4*)(W + (size_t)m2 * DIM + lane * 4);
    float p1 = xv.x * a.x + xv.y * a.y + xv.z * a.z + xv.w * a.w;
    float p2 = xv.x * b.x + xv.y * b.y + xv.z * b.z + xv.w * b.w;
    #pragma unroll
    for (int off = 32; off; off >>= 1) {
        p1 += __shfl_xor(p1, off);
        p2 += __shfl_xor(p2, off);
    }
    if (lane == 0) {
        float d1 = w2[m1] - 2.0f * p1;
        float d2 = w2[m2] - 2.0f * p2;
        int mw = (d2 < d1 || (d2 == d1 && m2 < m1)) ? m2 : m1;
        bmu[row] = mw;
        out_locs[row * 2 + 0] = (float)(mw >> 6);
        out_locs[row * 2 + 1] = (float)(mw & 63);
    }
}

// ---------------- scatter: per-cell accumulation ----------------
__global__ void k_scatter(const int* __restrict__ bmu, const float* __restrict__ X,
                          float* __restrict__ A, float* __restrict__ cnt) {
    const int b = blockIdx.x;
    const int m = bmu[b];
    const int d = threadIdx.x;
    atomicAdd(&A[(size_t)m * DIM + d], X[(size_t)b * DIM + d]);
    if (d == 0) atomicAdd(&cnt[m], 1.0f);
}

// ---------------- separable convolution pass 1 (over gj) ----------------
__global__ void k_conv1(const float* __restrict__ A, const float* __restrict__ E,
                        float* __restrict__ T1) {
    __shared__ float Es[64];
    const int d = threadIdx.x;
    if (d < 64) Es[d] = E[d];
    __syncthreads();
    const int gi = blockIdx.x >> 6, mj = blockIdx.x & 63;
    const float* base = A + (size_t)gi * 64 * DIM + d;
    float acc = 0.0f;
    #pragma unroll
    for (int gj = 0; gj < 64; ++gj) {
        int dd = mj - gj; dd = dd < 0 ? -dd : dd;
        acc += Es[dd] * base[(size_t)gj * DIM];
    }
    T1[(size_t)blockIdx.x * DIM + d] = acc;   // [gi][mj][d]
}

// ---------------- count convolutions (tiny) ----------------
__global__ void k_cnt1(const float* __restrict__ cnt, const float* __restrict__ E,
                       float* __restrict__ c1) {
    int t = blockIdx.x * 256 + threadIdx.x;   // 4096
    int gi = t >> 6, mj = t & 63;
    float acc = 0.0f;
    #pragma unroll
    for (int gj = 0; gj < 64; ++gj) {
        int dd = mj - gj; dd = dd < 0 ? -dd : dd;
        acc += E[dd] * cnt[gi * 64 + gj];
    }
    c1[gi * 64 + mj] = acc;
}
__global__ void k_cnt2(const float* __restrict__ c1, const float* __restrict__ E,
                       float* __restrict__ den) {
    int t = blockIdx.x * 256 + threadIdx.x;
    int mi = t >> 6, mj = t & 63;
    float acc = 0.0f;
    #pragma unroll
    for (int gi = 0; gi < 64; ++gi) {
        int dd = mi - gi; dd = dd < 0 ? -dd : dd;
        acc += E[dd] * c1[gi * 64 + mj];
    }
    den[mi * 64 + mj] = acc;
}

// ---------------- conv pass 2 (over gi) + divide + write ----------------
__global__ void k_conv2(const float* __restrict__ T1, const float* __restrict__ scal,
                        const float* __restrict__ den, float* __restrict__ outw) {
    __shared__ float Es[64];
    __shared__ float salpha;
    const int d = threadIdx.x;
    if (d < 64) Es[d] = scal[d];
    if (d == 64) salpha = scal[64];
    __syncthreads();
    const int mi = blockIdx.x >> 6, mj = blockIdx.x & 63;
    float acc = 0.0f;
    #pragma unroll
    for (int gi = 0; gi < 64; ++gi) {
        int dd = mi - gi; dd = dd < 0 ? -dd : dd;
        acc += Es[dd] * T1[((size_t)gi * 64 + mj) * DIM + d];
    }
    const float a = salpha;
    const float v = (a * acc) / (a * den[mi * 64 + mj] + 1e-12f);
    outw[((size_t)mi * 64 + mj) * DIM + d] = v;
}

// ---------------- launcher ----------------
extern "C" void kernel_launch(void* const* d_in, const int* in_sizes, int n_in,
                              void* d_out, int out_size, void* d_ws, size_t ws_size,
                              hipStream_t stream) {
    const float* X = (const float*)d_in[0];
    const float* W = (const float*)d_in[1];
    const int*   ep = (const int*)d_in[2];
    float* out = (float*)d_out;

    char* ws = (char*)d_ws;
    u64*   P1   = (u64*)(ws + 0);               // 64 KB
    u64*   P2   = (u64*)(ws + 65536);           // 64 KB
    int*   bmu  = (int*)(ws + 131072);          // 32 KB
    float* w2   = (float*)(ws + 163840);        // 16 KB
    float* scal = (float*)(ws + 180224);        // 4 KB (65 floats)
    float* cnt  = (float*)(ws + 184320);        // 16 KB
    float* c1   = (float*)(ws + 200704);        // 16 KB
    float* den  = (float*)(ws + 217088);        // 16 KB
    u16*   Xh   = (u16*)(ws + 262144);          // 4 MB
    u16*   Xl   = (u16*)(ws + 262144 + (4u<<20));  // 4 MB
    u16*   Wh   = (u16*)(ws + 262144 + (8u<<20));  // 2 MB
    u16*   Wl   = (u16*)(ws + 262144 + (10u<<20)); // 2 MB
    float* A    = (float*)(ws + 262144 + (8u<<20));   // 4 MB, aliases Wh/Wl (dead after gemm)
    float* T1   = (float*)(ws + 262144);              // 4 MB, aliases Xh (dead after gemm)

    hipMemsetAsync(ws, 0xFF, 131072, stream);                    // P1,P2 = +inf packed

    k_scal<<<1, 128, 0, stream>>>(ep, scal);
    k_w2<<<1024, 256, 0, stream>>>(W, w2);
    k_split<<<2048, 256, 0, stream>>>(X, Xh, Xl, BATCH * DIM / 4);
    k_split<<<1024, 256, 0, stream>>>(W, Wh, Wl, MCELL * DIM / 4);
    k_gemm_argmin<<<1024, 256, 0, stream>>>(Xh, Xl, Wh, Wl, w2, P1, P2);
    hipMemsetAsync(A, 0, 4u << 20, stream);                      // after gemm (aliases W splits)
    hipMemsetAsync(cnt, 0, 16384, stream);
    k_recheck<<<2048, 256, 0, stream>>>(P1, P2, X, W, w2, bmu, out);
    k_scatter<<<BATCH, 256, 0, stream>>>(bmu, X, A, cnt);
    k_conv1<<<4096, 256, 0, stream>>>(A, scal, T1);
    k_cnt1<<<16, 256, 0, stream>>>(cnt, scal, c1);
    k_cnt2<<<16, 256, 0, stream>>>(c1, scal, den);
    k_conv2<<<4096, 256, 0, stream>>>(T1, scal, den, out + 16384);
}